// Round 3
// baseline (592.543 us; speedup 1.0000x reference)
//
#include <hip/hip_runtime.h>
#include <hip/hip_bf16.h>
#include <stdint.h>

using bf16   = __hip_bfloat16;
using bf16x8 = __attribute__((ext_vector_type(8))) short;
using f32x4  = __attribute__((ext_vector_type(4))) float;

// ---- load 8 contiguous elems as bf16x8 (f32 source converts in-register) ----
__device__ __forceinline__ bf16x8 load8(const float* p) {
  f32x4 a = *(const f32x4*)p;
  f32x4 b = *(const f32x4*)(p + 4);
  bf16x8 r;
  bf16* rp = (bf16*)&r;
#pragma unroll
  for (int j = 0; j < 4; ++j) rp[j]     = __float2bfloat16(a[j]);
#pragma unroll
  for (int j = 0; j < 4; ++j) rp[4 + j] = __float2bfloat16(b[j]);
  return r;
}
__device__ __forceinline__ bf16x8 load8(const bf16* p) { return *(const bf16x8*)p; }

__device__ __forceinline__ void store_c(float* C, size_t i, float v) { C[i] = v; }
__device__ __forceinline__ void store_c(bf16*  C, size_t i, float v) { C[i] = __float2bfloat16(v); }

// ---------------- weight transpose: Wt[n][k] = bf16(W[k][n]) (1024x1024, f32 in) ----
__global__ __launch_bounds__(256)
void transpose_w(const float* __restrict__ w0, const float* __restrict__ w1,
                 const float* __restrict__ w2, const float* __restrict__ w3,
                 bf16* __restrict__ o0, bf16* __restrict__ o1,
                 bf16* __restrict__ o2, bf16* __restrict__ o3)
{
  __shared__ float tile[32][33];
  int z = blockIdx.z;
  const float* in = (z == 0) ? w0 : (z == 1) ? w1 : (z == 2) ? w2 : w3;
  bf16* out       = (z == 0) ? o0 : (z == 1) ? o1 : (z == 2) ? o2 : o3;
  int bx = blockIdx.x * 32, by = blockIdx.y * 32;
  int tx = threadIdx.x & 31, ty = threadIdx.x >> 5;
#pragma unroll
  for (int i = 0; i < 4; ++i)
    tile[ty + i * 8][tx] = in[(size_t)(by + ty + i * 8) * 1024 + bx + tx];
  __syncthreads();
#pragma unroll
  for (int i = 0; i < 4; ++i)
    out[(size_t)(bx + ty + i * 8) * 1024 + by + tx] = __float2bfloat16(tile[tx][ty + i * 8]);
}

// ---------------- T5 relative-position bias table: bias_tab[h][d], d = q-k >= 0 ----
__global__ __launch_bounds__(256)
void build_bias(const float* __restrict__ rpe, float* __restrict__ bias_tab)
{
  int idx = blockIdx.x * 256 + threadIdx.x;   // 16 heads * 4096 distances
  int d = idx >> 4, h = idx & 15;
  int b;
  if (d < 16) {
    b = d;
  } else {
    // thresholds for 16 + floor(16*log(d/16)/log(256)); power-of-2 boundaries inclusive
    const int T[15] = {23, 32, 46, 64, 91, 128, 182, 256, 363, 512,
                       725, 1024, 1449, 2048, 2897};
    int m = 0;
#pragma unroll
    for (int i = 0; i < 15; ++i) m += (d >= T[i]);
    b = 16 + m;
  }
  bias_tab[h * 4096 + d] = rpe[b * 16 + h];
}

// ---------------- GEMM: C[4096,1024] = A[4096,1024] @ W + bias (Wt = W^T given) ----
// 128x128 tile, BK=64, 4 waves (2x2), each wave 64x64 via 4x4 mfma_16x16x32 frags.
// Reg-staged LDS; XOR swizzle (16B slots ^ row&7) applied on BOTH write and read.
template <typename AT, typename OT>
__device__ __forceinline__ void gemm_body(const AT* __restrict__ A,
                                          const bf16* __restrict__ Wt,
                                          const float* __restrict__ bias,
                                          OT* __restrict__ C)
{
  __shared__ bf16 As[128 * 64];
  __shared__ bf16 Bs[128 * 64];
  const int tid = threadIdx.x;
  const int lane = tid & 63, wid = tid >> 6;
  const int l15 = lane & 15, lg = lane >> 4;
  const int wr = wid >> 1, wc = wid & 1;
  const int m0 = blockIdx.x * 128, n0 = blockIdx.y * 128;

  f32x4 acc[4][4];
#pragma unroll
  for (int i = 0; i < 4; ++i)
#pragma unroll
    for (int j = 0; j < 4; ++j) acc[i][j] = (f32x4){0.f, 0.f, 0.f, 0.f};

#pragma unroll 1
  for (int kt = 0; kt < 16; ++kt) {
    const int k0 = kt * 64;
    __syncthreads();
    bf16x8 ra[4], rb[4];
#pragma unroll
    for (int it = 0; it < 4; ++it) {
      const int ci = tid + it * 256;            // 1024 chunks of 8 elems
      const int row = ci >> 3, s = ci & 7;
      ra[it] = load8(A  + (size_t)(m0 + row) * 1024 + k0 + s * 8);
      rb[it] = load8(Wt + (size_t)(n0 + row) * 1024 + k0 + s * 8);
    }
#pragma unroll
    for (int it = 0; it < 4; ++it) {
      const int ci = tid + it * 256;
      const int row = ci >> 3, s = ci & 7;
      const int off = row * 128 + ((s ^ (row & 7)) << 4);
      *(bf16x8*)((char*)As + off) = ra[it];
      *(bf16x8*)((char*)Bs + off) = rb[it];
    }
    __syncthreads();

    bf16x8 af[2][4], bfr[2][4];
#pragma unroll
    for (int ks = 0; ks < 2; ++ks) {
      const int s8 = ks * 4 + lg;
#pragma unroll
      for (int f = 0; f < 4; ++f) {
        const int ra_ = wr * 64 + f * 16 + l15;
        af[ks][f]  = *(const bf16x8*)((const char*)As + ra_ * 128 + ((s8 ^ (ra_ & 7)) << 4));
        const int rb_ = wc * 64 + f * 16 + l15;
        bfr[ks][f] = *(const bf16x8*)((const char*)Bs + rb_ * 128 + ((s8 ^ (rb_ & 7)) << 4));
      }
    }
#pragma unroll
    for (int ks = 0; ks < 2; ++ks)
#pragma unroll
      for (int mf = 0; mf < 4; ++mf)
#pragma unroll
        for (int nf = 0; nf < 4; ++nf)
          acc[mf][nf] = __builtin_amdgcn_mfma_f32_16x16x32_bf16(
              af[ks][mf], bfr[ks][nf], acc[mf][nf], 0, 0, 0);
  }

#pragma unroll
  for (int nf = 0; nf < 4; ++nf) {
    const int col = n0 + wc * 64 + nf * 16 + l15;
    const float bv = bias[col];
#pragma unroll
    for (int mf = 0; mf < 4; ++mf) {
      const int rowb = m0 + wr * 64 + mf * 16 + lg * 4;
#pragma unroll
      for (int r = 0; r < 4; ++r)
        store_c(C, (size_t)(rowb + r) * 1024 + col, acc[mf][nf][r] + bv);
    }
  }
}

__global__ __launch_bounds__(256)
void gemm_qkv(const float* __restrict__ xq, const float* __restrict__ xk,
              const float* __restrict__ xv,
              const bf16* __restrict__ wqt, const bf16* __restrict__ wkt,
              const bf16* __restrict__ wvt,
              const float* __restrict__ bq, const float* __restrict__ bk,
              const float* __restrict__ bv,
              bf16* __restrict__ Q, bf16* __restrict__ K, bf16* __restrict__ V)
{
  int z = blockIdx.z;
  gemm_body<float, bf16>(z == 0 ? xq : z == 1 ? xk : xv,
                         z == 0 ? wqt : z == 1 ? wkt : wvt,
                         z == 0 ? bq : z == 1 ? bk : bv,
                         z == 0 ? Q : z == 1 ? K : V);
}

__global__ __launch_bounds__(256)
void gemm_out(const bf16* __restrict__ A, const bf16* __restrict__ Wt,
              const float* __restrict__ bias, float* __restrict__ C)
{
  gemm_body<bf16, float>(A, Wt, bias, C);
}

// ---------------- causal flash attention + T5 bias ----------------
// grid (S/64, H); block 256 = 4 waves; wave w owns q rows [q0+16w, q0+16w+16)
// KV tile = 64. K in LDS (swizzled, reg-staged). V staged TRANSPOSED: Vt[d][k], stride 72.
__global__ __launch_bounds__(256)
void attn_kernel(const bf16* __restrict__ Qb, const bf16* __restrict__ Kb,
                 const bf16* __restrict__ Vb, const float* __restrict__ bias_tab,
                 bf16* __restrict__ Ob)
{
  __shared__ bf16 Ks[64 * 64];
  __shared__ bf16 Vt[64 * 72];      // Vt[d][k], rows padded to 72 (144B, 16B-aligned)
  __shared__ bf16 Pl[4][16 * 72];   // per-wave P strip, stride 72 (144B)

  const int tid = threadIdx.x;
  const int lane = tid & 63, wid = tid >> 6;
  const int l15 = lane & 15, lg = lane >> 4;
  const int q0 = blockIdx.x * 64;
  const int h = blockIdx.y;
  const int qw = q0 + wid * 16;

  bf16x8 qf[2];
  {
    const bf16* qp = Qb + (size_t)(qw + l15) * 1024 + h * 64 + lg * 8;
    qf[0] = *(const bf16x8*)qp;
    qf[1] = *(const bf16x8*)(qp + 32);
  }

  f32x4 o_acc[4];
#pragma unroll
  for (int nf = 0; nf < 4; ++nf) o_acc[nf] = (f32x4){0.f, 0.f, 0.f, 0.f};
  float m_run[4] = {-1e30f, -1e30f, -1e30f, -1e30f};
  float l_run[4] = {0.f, 0.f, 0.f, 0.f};

  bf16* pw = &Pl[wid][0];
  const int ntiles = blockIdx.x + 1;   // causal: k0 <= q0+63

#pragma unroll 1
  for (int t = 0; t < ntiles; ++t) {
    const int k0 = t * 64;
    __syncthreads();
    // stage K (swizzled rows of 8 slots) and V (transposed) via registers
    bf16x8 rk[2], rv[2];
#pragma unroll
    for (int it = 0; it < 2; ++it) {
      const int ci = tid + it * 256;            // 512 chunks of 8 elems
      const int row = ci >> 3, s = ci & 7;
      rk[it] = *(const bf16x8*)(Kb + (size_t)(k0 + row) * 1024 + h * 64 + s * 8);
      rv[it] = *(const bf16x8*)(Vb + (size_t)(k0 + row) * 1024 + h * 64 + s * 8);
    }
#pragma unroll
    for (int it = 0; it < 2; ++it) {
      const int ci = tid + it * 256;
      const int row = ci >> 3, s = ci & 7;
      *(bf16x8*)((char*)Ks + row * 128 + ((s ^ (row & 7)) << 4)) = rk[it];
      // V transpose: V[row][s*8+j] -> Vt[s*8+j][row]
      const bf16* ve = (const bf16*)&rv[it];
#pragma unroll
      for (int j = 0; j < 8; ++j)
        Vt[(s * 8 + j) * 72 + row] = ve[j];
    }
    __syncthreads();

    // S = Q K^T  (rows: this wave's 16 q; cols: 64 k)
    f32x4 s[4];
#pragma unroll
    for (int nf = 0; nf < 4; ++nf) s[nf] = (f32x4){0.f, 0.f, 0.f, 0.f};
#pragma unroll
    for (int nf = 0; nf < 4; ++nf) {
      const int rk_ = nf * 16 + l15;
#pragma unroll
      for (int ks = 0; ks < 2; ++ks) {
        const int s8 = ks * 4 + lg;
        bf16x8 kf = *(const bf16x8*)((const char*)Ks + rk_ * 128 + ((s8 ^ (rk_ & 7)) << 4));
        s[nf] = __builtin_amdgcn_mfma_f32_16x16x32_bf16(qf[ks], kf, s[nf], 0, 0, 0);
      }
    }

    // scale + rpe bias + causal mask; per-row tile max
    float mt[4] = {-1e30f, -1e30f, -1e30f, -1e30f};
#pragma unroll
    for (int nf = 0; nf < 4; ++nf) {
      const int kk = k0 + nf * 16 + l15;
      const int dbase = (qw + lg * 4) - kk;
#pragma unroll
      for (int r = 0; r < 4; ++r) {
        const int d = dbase + r;
        float sv = (d >= 0) ? (s[nf][r] * 0.125f + bias_tab[h * 4096 + d]) : -1e30f;
        s[nf][r] = sv;
        mt[r] = fmaxf(mt[r], sv);
      }
    }
#pragma unroll
    for (int r = 0; r < 4; ++r) {
      float v = mt[r];
      v = fmaxf(v, __shfl_xor(v, 1, 64));
      v = fmaxf(v, __shfl_xor(v, 2, 64));
      v = fmaxf(v, __shfl_xor(v, 4, 64));
      v = fmaxf(v, __shfl_xor(v, 8, 64));
      mt[r] = v;
    }
    // online softmax update (NaN-proof: sentinel values never enter exp)
#pragma unroll
    for (int r = 0; r < 4; ++r) {
      const float newm = fmaxf(m_run[r], mt[r]);
      const float sc = (m_run[r] > -1e29f) ? __expf(m_run[r] - newm) : 0.f;
      m_run[r] = newm;
      float rs = 0.f;
#pragma unroll
      for (int nf = 0; nf < 4; ++nf) {
        const float p = (s[nf][r] > -1e29f) ? __expf(s[nf][r] - newm) : 0.f;
        s[nf][r] = p;
        rs += p;
      }
      rs += __shfl_xor(rs, 1, 64);
      rs += __shfl_xor(rs, 2, 64);
      rs += __shfl_xor(rs, 4, 64);
      rs += __shfl_xor(rs, 8, 64);
      l_run[r] = l_run[r] * sc + rs;
#pragma unroll
      for (int nf = 0; nf < 4; ++nf) o_acc[nf][r] *= sc;
    }

    // P -> bf16 via per-wave LDS round trip (D-layout write, A-layout read)
#pragma unroll
    for (int nf = 0; nf < 4; ++nf)
#pragma unroll
      for (int r = 0; r < 4; ++r)
        pw[(lg * 4 + r) * 72 + nf * 16 + l15] = __float2bfloat16(s[nf][r]);

    bf16x8 pf[2];
#pragma unroll
    for (int ks2 = 0; ks2 < 2; ++ks2)
      pf[ks2] = *(const bf16x8*)&pw[l15 * 72 + ks2 * 32 + lg * 8];

    // PV: B-fragment lane l needs V[k = ks2*32+lg*8+j][d = nf*16+l15] = Vt[d][k..k+7]
#pragma unroll
    for (int ks2 = 0; ks2 < 2; ++ks2)
#pragma unroll
      for (int nf = 0; nf < 4; ++nf) {
        bf16x8 vfrag = *(const bf16x8*)&Vt[(nf * 16 + l15) * 72 + ks2 * 32 + lg * 8];
        o_acc[nf] = __builtin_amdgcn_mfma_f32_16x16x32_bf16(pf[ks2], vfrag, o_acc[nf],
                                                            0, 0, 0);
      }
  }

  // epilogue: O / l, store [S, H*64]
#pragma unroll
  for (int nf = 0; nf < 4; ++nf)
#pragma unroll
    for (int r = 0; r < 4; ++r) {
      const int row = qw + lg * 4 + r;
      Ob[(size_t)row * 1024 + h * 64 + nf * 16 + l15] =
          __float2bfloat16(o_acc[nf][r] / l_run[r]);
    }
}

// ---------------- launch ----------------
extern "C" void kernel_launch(void* const* d_in, const int* in_sizes, int n_in,
                              void* d_out, int out_size, void* d_ws, size_t ws_size,
                              hipStream_t stream) {
  (void)in_sizes; (void)n_in; (void)out_size; (void)ws_size;
  const float* q   = (const float*)d_in[0];
  const float* k   = (const float*)d_in[1];
  const float* v   = (const float*)d_in[2];
  // d_in[3] = causal mask, deterministic -> ignored
  const float* Wq  = (const float*)d_in[4];
  const float* bq  = (const float*)d_in[5];
  const float* Wk  = (const float*)d_in[6];
  const float* bk  = (const float*)d_in[7];
  const float* Wv  = (const float*)d_in[8];
  const float* bv  = (const float*)d_in[9];
  const float* Wo  = (const float*)d_in[10];
  const float* bo  = (const float*)d_in[11];
  const float* rpe = (const float*)d_in[12];
  float* out = (float*)d_out;

  char* ws = (char*)d_ws;
  bf16* WqT = (bf16*)(ws + (size_t)0);
  bf16* WkT = (bf16*)(ws + ((size_t)2 << 20));
  bf16* WvT = (bf16*)(ws + ((size_t)4 << 20));
  bf16* WoT = (bf16*)(ws + ((size_t)6 << 20));
  bf16* Qb  = (bf16*)(ws + ((size_t)8 << 20));
  bf16* Kb  = (bf16*)(ws + ((size_t)16 << 20));
  bf16* Vb  = (bf16*)(ws + ((size_t)24 << 20));
  bf16* Ob  = (bf16*)(ws + ((size_t)32 << 20));
  float* bias_tab = (float*)(ws + ((size_t)40 << 20));

  transpose_w<<<dim3(32, 32, 4), 256, 0, stream>>>(Wq, Wk, Wv, Wo, WqT, WkT, WvT, WoT);
  build_bias<<<dim3(256), 256, 0, stream>>>(rpe, bias_tab);
  gemm_qkv<<<dim3(32, 8, 3), 256, 0, stream>>>(q, k, v, WqT, WkT, WvT,
                                               bq, bk, bv, Qb, Kb, Vb);
  attn_kernel<<<dim3(64, 16), 256, 0, stream>>>(Qb, Kb, Vb, bias_tab, Ob);
  gemm_out<<<dim3(32, 8), 256, 0, stream>>>(Ob, WoT, bo, out);
}

// Round 4
// 374.518 us; speedup vs baseline: 1.5821x; 1.5821x over previous
//
#include <hip/hip_runtime.h>
#include <hip/hip_bf16.h>
#include <stdint.h>

using bf16   = __hip_bfloat16;
using bf16x8 = __attribute__((ext_vector_type(8))) short;
using bf16x4 = __attribute__((ext_vector_type(4))) short;
using f32x4  = __attribute__((ext_vector_type(4))) float;

// ---- load 8 contiguous elems as bf16x8 (f32 source converts in-register) ----
__device__ __forceinline__ bf16x8 load8(const float* p) {
  f32x4 a = *(const f32x4*)p;
  f32x4 b = *(const f32x4*)(p + 4);
  bf16x8 r;
  bf16* rp = (bf16*)&r;
#pragma unroll
  for (int j = 0; j < 4; ++j) rp[j]     = __float2bfloat16(a[j]);
#pragma unroll
  for (int j = 0; j < 4; ++j) rp[4 + j] = __float2bfloat16(b[j]);
  return r;
}
__device__ __forceinline__ bf16x8 load8(const bf16* p) { return *(const bf16x8*)p; }

// ---------------- weight transpose: Wt[n][k] = bf16(W[k][n]) (1024x1024, f32 in) ----
__global__ __launch_bounds__(256)
void transpose_w(const float* __restrict__ w0, const float* __restrict__ w1,
                 const float* __restrict__ w2, const float* __restrict__ w3,
                 bf16* __restrict__ o0, bf16* __restrict__ o1,
                 bf16* __restrict__ o2, bf16* __restrict__ o3)
{
  __shared__ float tile[32][33];
  int z = blockIdx.z;
  const float* in = (z == 0) ? w0 : (z == 1) ? w1 : (z == 2) ? w2 : w3;
  bf16* out       = (z == 0) ? o0 : (z == 1) ? o1 : (z == 2) ? o2 : o3;
  int bx = blockIdx.x * 32, by = blockIdx.y * 32;
  int tx = threadIdx.x & 31, ty = threadIdx.x >> 5;
#pragma unroll
  for (int i = 0; i < 4; ++i)
    tile[ty + i * 8][tx] = in[(size_t)(by + ty + i * 8) * 1024 + bx + tx];
  __syncthreads();
#pragma unroll
  for (int i = 0; i < 4; ++i)
    out[(size_t)(bx + ty + i * 8) * 1024 + by + tx] = __float2bfloat16(tile[tx][ty + i * 8]);
}

// ---------------- T5 relative-position bias table: bias_tab[h][d], d = q-k >= 0 ----
__global__ __launch_bounds__(256)
void build_bias(const float* __restrict__ rpe, float* __restrict__ bias_tab)
{
  int idx = blockIdx.x * 256 + threadIdx.x;   // 16 heads * 4096 distances
  int d = idx >> 4, h = idx & 15;
  int b;
  if (d < 16) {
    b = d;
  } else {
    const int T[15] = {23, 32, 46, 64, 91, 128, 182, 256, 363, 512,
                       725, 1024, 1449, 2048, 2897};
    int m = 0;
#pragma unroll
    for (int i = 0; i < 15; ++i) m += (d >= T[i]);
    b = 16 + m;
  }
  bias_tab[h * 4096 + d] = rpe[b * 16 + h];
}

// ---------------- GEMM: C[4096,1024] = A[4096,1024] @ W + bias (Wt = W^T given) ----
// 128x128 tile, BK=64, 4 waves (2x2), each wave 64x64 via 4x4 mfma_16x16x32 frags.
// VT=true: store transposed per head -> C[h][d][row] with h=col>>6, d=col&63.
template <typename AT, typename OT, bool VT>
__device__ __forceinline__ void gemm_body(const AT* __restrict__ A,
                                          const bf16* __restrict__ Wt,
                                          const float* __restrict__ bias,
                                          OT* __restrict__ C)
{
  __shared__ bf16 As[128 * 64];
  __shared__ bf16 Bs[128 * 64];
  const int tid = threadIdx.x;
  const int lane = tid & 63, wid = tid >> 6;
  const int l15 = lane & 15, lg = lane >> 4;
  const int wr = wid >> 1, wc = wid & 1;
  const int m0 = blockIdx.x * 128, n0 = blockIdx.y * 128;

  f32x4 acc[4][4];
#pragma unroll
  for (int i = 0; i < 4; ++i)
#pragma unroll
    for (int j = 0; j < 4; ++j) acc[i][j] = (f32x4){0.f, 0.f, 0.f, 0.f};

#pragma unroll 1
  for (int kt = 0; kt < 16; ++kt) {
    const int k0 = kt * 64;
    __syncthreads();
    bf16x8 ra[4], rb[4];
#pragma unroll
    for (int it = 0; it < 4; ++it) {
      const int ci = tid + it * 256;
      const int row = ci >> 3, s = ci & 7;
      ra[it] = load8(A  + (size_t)(m0 + row) * 1024 + k0 + s * 8);
      rb[it] = load8(Wt + (size_t)(n0 + row) * 1024 + k0 + s * 8);
    }
#pragma unroll
    for (int it = 0; it < 4; ++it) {
      const int ci = tid + it * 256;
      const int row = ci >> 3, s = ci & 7;
      const int off = row * 128 + ((s ^ (row & 7)) << 4);
      *(bf16x8*)((char*)As + off) = ra[it];
      *(bf16x8*)((char*)Bs + off) = rb[it];
    }
    __syncthreads();

    bf16x8 af[2][4], bfr[2][4];
#pragma unroll
    for (int ks = 0; ks < 2; ++ks) {
      const int s8 = ks * 4 + lg;
#pragma unroll
      for (int f = 0; f < 4; ++f) {
        const int ra_ = wr * 64 + f * 16 + l15;
        af[ks][f]  = *(const bf16x8*)((const char*)As + ra_ * 128 + ((s8 ^ (ra_ & 7)) << 4));
        const int rb_ = wc * 64 + f * 16 + l15;
        bfr[ks][f] = *(const bf16x8*)((const char*)Bs + rb_ * 128 + ((s8 ^ (rb_ & 7)) << 4));
      }
    }
#pragma unroll
    for (int ks = 0; ks < 2; ++ks)
#pragma unroll
      for (int mf = 0; mf < 4; ++mf)
#pragma unroll
        for (int nf = 0; nf < 4; ++nf)
          acc[mf][nf] = __builtin_amdgcn_mfma_f32_16x16x32_bf16(
              af[ks][mf], bfr[ks][nf], acc[mf][nf], 0, 0, 0);
  }

#pragma unroll
  for (int nf = 0; nf < 4; ++nf) {
    const int col = n0 + wc * 64 + nf * 16 + l15;
    const float bv = bias[col];
#pragma unroll
    for (int mf = 0; mf < 4; ++mf) {
      const int rowb = m0 + wr * 64 + mf * 16 + lg * 4;
#pragma unroll
      for (int r = 0; r < 4; ++r) {
        const float val = acc[mf][nf][r] + bv;
        if (VT) {
          ((bf16*)C)[((size_t)(col >> 6) << 18) + ((size_t)(col & 63) << 12) + rowb + r] =
              __float2bfloat16(val);
        } else if (sizeof(OT) == 4) {
          ((float*)C)[(size_t)(rowb + r) * 1024 + col] = val;
        } else {
          ((bf16*)C)[(size_t)(rowb + r) * 1024 + col] = __float2bfloat16(val);
        }
      }
    }
  }
}

__global__ __launch_bounds__(256)
void gemm_qk(const float* __restrict__ xq, const float* __restrict__ xk,
             const bf16* __restrict__ wqt, const bf16* __restrict__ wkt,
             const float* __restrict__ bq, const float* __restrict__ bk,
             bf16* __restrict__ Q, bf16* __restrict__ K)
{
  int z = blockIdx.z;
  gemm_body<float, bf16, false>(z == 0 ? xq : xk, z == 0 ? wqt : wkt,
                                z == 0 ? bq : bk, z == 0 ? Q : K);
}

__global__ __launch_bounds__(256)
void gemm_v(const float* __restrict__ xv, const bf16* __restrict__ wvt,
            const float* __restrict__ bv, bf16* __restrict__ VtG)
{
  gemm_body<float, bf16, true>(xv, wvt, bv, VtG);
}

__global__ __launch_bounds__(256)
void gemm_out(const bf16* __restrict__ A, const bf16* __restrict__ Wt,
              const float* __restrict__ bias, float* __restrict__ C)
{
  gemm_body<bf16, float, false>(A, Wt, bias, C);
}

// ---------------- causal flash attention + T5 bias (swapped QK^T) ----------------
// grid 1024 blocks; bid -> (h = bid&15, qt = 63 - bid>>4) : work-descending dispatch,
// heads clustered mod 8 for XCD L2 reuse. 4 waves x 16 q-rows, KV tile 64.
// K staged [k][d] swizzled; V staged from global V^T [d][k] swizzled. All LDS b128.
__global__ __launch_bounds__(256)
void attn_kernel(const bf16* __restrict__ Qb, const bf16* __restrict__ Kb,
                 const bf16* __restrict__ VtG, const float* __restrict__ bias_tab,
                 bf16* __restrict__ Ob)
{
  __shared__ bf16 Ks[64 * 64];
  __shared__ bf16 Vs[64 * 64];
  __shared__ bf16 Pl[4][16 * 76];   // per-wave P strip, stride 76 elems

  const int tid = threadIdx.x;
  const int lane = tid & 63, wid = tid >> 6;
  const int l15 = lane & 15, lg = lane >> 4;
  const int bid = blockIdx.x;
  const int h  = bid & 15;
  const int qt = 63 - (bid >> 4);
  const int nt = qt + 1;
  const int qw = qt * 64 + wid * 16;
  const int q_abs = qw + l15;

  const bf16* Kh = Kb + h * 64;
  const bf16* Vh = VtG + ((size_t)h << 18);
  const float* bh = bias_tab + h * 4096;
  bf16* pw = &Pl[wid][0];

  // staging thread mapping: 512 chunks of 8 elems = 64 rows x 8 slots
  const int kr0 = tid >> 3, ks0_ = tid & 7;
  const int kr1 = (tid + 256) >> 3, ks1_ = tid & 7;

  bf16x8 qf[2];
  {
    const bf16* qp = Qb + (size_t)q_abs * 1024 + h * 64 + lg * 8;
    qf[0] = *(const bf16x8*)qp;
    qf[1] = *(const bf16x8*)(qp + 32);
  }

  f32x4 o_acc[4];
#pragma unroll
  for (int nf = 0; nf < 4; ++nf) o_acc[nf] = (f32x4){0.f, 0.f, 0.f, 0.f};
  float m_run = -1e30f, l_run = 0.f;

  // prologue: load tile 0 into regs
  bf16x8 rk0 = *(const bf16x8*)(Kh + (size_t)kr0 * 1024 + ks0_ * 8);
  bf16x8 rk1 = *(const bf16x8*)(Kh + (size_t)kr1 * 1024 + ks1_ * 8);
  bf16x8 rv0 = *(const bf16x8*)(Vh + (size_t)kr0 * 4096 + ks0_ * 8);
  bf16x8 rv1 = *(const bf16x8*)(Vh + (size_t)kr1 * 4096 + ks1_ * 8);

#pragma unroll 1
  for (int t = 0; t < nt; ++t) {
    const int k0 = t * 64;
    __syncthreads();
    {
      const int o0 = kr0 * 128 + ((ks0_ ^ (kr0 & 7)) << 4);
      const int o1 = kr1 * 128 + ((ks1_ ^ (kr1 & 7)) << 4);
      *(bf16x8*)((char*)Ks + o0) = rk0;
      *(bf16x8*)((char*)Ks + o1) = rk1;
      *(bf16x8*)((char*)Vs + o0) = rv0;
      *(bf16x8*)((char*)Vs + o1) = rv1;
    }
    __syncthreads();
    if (t + 1 < nt) {   // prefetch next tile (hidden under compute)
      const int k1 = k0 + 64;
      rk0 = *(const bf16x8*)(Kh + (size_t)(k1 + kr0) * 1024 + ks0_ * 8);
      rk1 = *(const bf16x8*)(Kh + (size_t)(k1 + kr1) * 1024 + ks1_ * 8);
      rv0 = *(const bf16x8*)(Vh + (size_t)kr0 * 4096 + k1 + ks0_ * 8);
      rv1 = *(const bf16x8*)(Vh + (size_t)kr1 * 4096 + k1 + ks1_ * 8);
    }

    // S^T = K . Q^T : lane holds S[q = q_abs][k = k0 + kf*16 + lg*4 + r]
    f32x4 st[4];
#pragma unroll
    for (int kf = 0; kf < 4; ++kf) st[kf] = (f32x4){0.f, 0.f, 0.f, 0.f};
#pragma unroll
    for (int kf = 0; kf < 4; ++kf) {
      const int row = kf * 16 + l15;
#pragma unroll
      for (int ks = 0; ks < 2; ++ks) {
        const int s8 = ks * 4 + lg;
        bf16x8 kfr = *(const bf16x8*)((const char*)Ks + row * 128 + ((s8 ^ (row & 7)) << 4));
        st[kf] = __builtin_amdgcn_mfma_f32_16x16x32_bf16(kfr, qf[ks], st[kf], 0, 0, 0);
      }
    }

    // bias with -1e30 sentinel on masked (d<0) positions
    float bvr[4][4];
#pragma unroll
    for (int kf = 0; kf < 4; ++kf)
#pragma unroll
      for (int r = 0; r < 4; ++r) {
        const int d = q_abs - (k0 + kf * 16 + lg * 4 + r);
        bvr[kf][r] = (d >= 0) ? bh[d] : -1e30f;
      }

    float mt = -1e30f;
#pragma unroll
    for (int kf = 0; kf < 4; ++kf)
#pragma unroll
      for (int r = 0; r < 4; ++r) {
        const float sv = st[kf][r] * 0.125f + bvr[kf][r];
        st[kf][r] = sv;
        mt = fmaxf(mt, sv);
      }
    mt = fmaxf(mt, __shfl_xor(mt, 16, 64));
    mt = fmaxf(mt, __shfl_xor(mt, 32, 64));

    const float newm = fmaxf(m_run, mt);
    const float sc = (m_run > -1e29f) ? __expf(m_run - newm) : 0.f;
    m_run = newm;

    float rs = 0.f;
    bf16x4 pk[4];
#pragma unroll
    for (int kf = 0; kf < 4; ++kf)
#pragma unroll
      for (int r = 0; r < 4; ++r) {
        const float p = (st[kf][r] > -1e29f) ? __expf(st[kf][r] - newm) : 0.f;
        ((bf16*)&pk[kf])[r] = __float2bfloat16(p);
        rs += p;
      }
    rs += __shfl_xor(rs, 16, 64);
    rs += __shfl_xor(rs, 32, 64);
    l_run = l_run * sc + rs;

    // P strip: lane writes its 4 consecutive k per kf (b64)
#pragma unroll
    for (int kf = 0; kf < 4; ++kf)
      *(bf16x4*)&pw[l15 * 76 + kf * 16 + lg * 4] = pk[kf];

    // redistribute rescale factor to O layout (q = lg*4+r)
    float scr[4];
#pragma unroll
    for (int r = 0; r < 4; ++r) scr[r] = __shfl(sc, lg * 4 + r, 64);
#pragma unroll
    for (int nf = 0; nf < 4; ++nf)
#pragma unroll
      for (int r = 0; r < 4; ++r) o_acc[nf][r] *= scr[r];

    // PV: A = P (q rows), B = V^T-staged (d cols, k contiguous)
    bf16x8 pf[2];
#pragma unroll
    for (int ks2 = 0; ks2 < 2; ++ks2)
      pf[ks2] = *(const bf16x8*)&pw[l15 * 76 + ks2 * 32 + lg * 8];
#pragma unroll
    for (int ks2 = 0; ks2 < 2; ++ks2)
#pragma unroll
      for (int nf = 0; nf < 4; ++nf) {
        const int row = nf * 16 + l15;
        const int s8 = ks2 * 4 + lg;
        bf16x8 vfr = *(const bf16x8*)((const char*)Vs + row * 128 + ((s8 ^ (row & 7)) << 4));
        o_acc[nf] = __builtin_amdgcn_mfma_f32_16x16x32_bf16(pf[ks2], vfr, o_acc[nf], 0, 0, 0);
      }
  }

  // epilogue: O / l, store [S, H*64]
  const float linv = 1.f / l_run;
  float lr[4];
#pragma unroll
  for (int r = 0; r < 4; ++r) lr[r] = __shfl(linv, lg * 4 + r, 64);
#pragma unroll
  for (int nf = 0; nf < 4; ++nf)
#pragma unroll
    for (int r = 0; r < 4; ++r) {
      const int row = qw + lg * 4 + r;
      Ob[(size_t)row * 1024 + h * 64 + nf * 16 + l15] =
          __float2bfloat16(o_acc[nf][r] * lr[r]);
    }
}

// ---------------- launch ----------------
extern "C" void kernel_launch(void* const* d_in, const int* in_sizes, int n_in,
                              void* d_out, int out_size, void* d_ws, size_t ws_size,
                              hipStream_t stream) {
  (void)in_sizes; (void)n_in; (void)out_size; (void)ws_size;
  const float* q   = (const float*)d_in[0];
  const float* k   = (const float*)d_in[1];
  const float* v   = (const float*)d_in[2];
  // d_in[3] = causal mask, deterministic -> ignored
  const float* Wq  = (const float*)d_in[4];
  const float* bq  = (const float*)d_in[5];
  const float* Wk  = (const float*)d_in[6];
  const float* bk  = (const float*)d_in[7];
  const float* Wv  = (const float*)d_in[8];
  const float* bv  = (const float*)d_in[9];
  const float* Wo  = (const float*)d_in[10];
  const float* bo  = (const float*)d_in[11];
  const float* rpe = (const float*)d_in[12];
  float* out = (float*)d_out;

  char* ws = (char*)d_ws;
  bf16* WqT = (bf16*)(ws + (size_t)0);
  bf16* WkT = (bf16*)(ws + ((size_t)2 << 20));
  bf16* WvT = (bf16*)(ws + ((size_t)4 << 20));
  bf16* WoT = (bf16*)(ws + ((size_t)6 << 20));
  bf16* Qb  = (bf16*)(ws + ((size_t)8 << 20));
  bf16* Kb  = (bf16*)(ws + ((size_t)16 << 20));
  bf16* VtG = (bf16*)(ws + ((size_t)24 << 20));   // [16][64][4096]
  bf16* Ob  = (bf16*)(ws + ((size_t)32 << 20));
  float* bias_tab = (float*)(ws + ((size_t)40 << 20));

  transpose_w<<<dim3(32, 32, 4), 256, 0, stream>>>(Wq, Wk, Wv, Wo, WqT, WkT, WvT, WoT);
  build_bias<<<dim3(256), 256, 0, stream>>>(rpe, bias_tab);
  gemm_qk<<<dim3(32, 8, 2), 256, 0, stream>>>(q, k, WqT, WkT, bq, bk, Qb, Kb);
  gemm_v<<<dim3(32, 8), 256, 0, stream>>>(v, WvT, bv, VtG);
  attn_kernel<<<dim3(1024), 256, 0, stream>>>(Qb, Kb, VtG, bias_tab, Ob);
  gemm_out<<<dim3(32, 8), 256, 0, stream>>>(Ob, WoT, bo, out);
}

// Round 5
// 355.520 us; speedup vs baseline: 1.6667x; 1.0534x over previous
//
#include <hip/hip_runtime.h>
#include <hip/hip_bf16.h>
#include <stdint.h>

using bf16   = __hip_bfloat16;
using bf16x8 = __attribute__((ext_vector_type(8))) short;
using bf16x4 = __attribute__((ext_vector_type(4))) short;
using f32x4  = __attribute__((ext_vector_type(4))) float;
using f32x4a = __attribute__((ext_vector_type(4), aligned(4))) float;

// async global->LDS, 16B/lane. LDS dest must be wave-uniform; HW adds lane*16.
__device__ __forceinline__ void g2l16(const void* g, void* l) {
  __builtin_amdgcn_global_load_lds(
      (const __attribute__((address_space(1))) void*)g,
      (__attribute__((address_space(3))) void*)l, 16, 0, 0);
}

// ---- load 8 contiguous f32 -> bf16x8 ----
__device__ __forceinline__ bf16x8 load8(const float* p) {
  f32x4 a = *(const f32x4*)p;
  f32x4 b = *(const f32x4*)(p + 4);
  bf16x8 r;
  bf16* rp = (bf16*)&r;
#pragma unroll
  for (int j = 0; j < 4; ++j) rp[j]     = __float2bfloat16(a[j]);
#pragma unroll
  for (int j = 0; j < 4; ++j) rp[4 + j] = __float2bfloat16(b[j]);
  return r;
}

// ---------------- f32 -> bf16 conversion prepass (q,k,v) ----------------
__global__ __launch_bounds__(256)
void cvt_bf16(const float* __restrict__ a, const float* __restrict__ b,
              const float* __restrict__ c, bf16* __restrict__ oa,
              bf16* __restrict__ ob, bf16* __restrict__ oc)
{
  const int z = blockIdx.z;
  const float* src = (z == 0) ? a : (z == 1) ? b : c;
  bf16* dst        = (z == 0) ? oa : (z == 1) ? ob : oc;
  const int i = (blockIdx.x * 256 + threadIdx.x) * 8;   // grid.x = 2048 covers 4M elems
  *(bf16x8*)(dst + i) = load8(src + i);
}

// ---------------- weight transpose: Wt[n][k] = bf16(W[k][n]) ----------------
__global__ __launch_bounds__(256)
void transpose_w(const float* __restrict__ w0, const float* __restrict__ w1,
                 const float* __restrict__ w2, const float* __restrict__ w3,
                 bf16* __restrict__ o0, bf16* __restrict__ o1,
                 bf16* __restrict__ o2, bf16* __restrict__ o3)
{
  __shared__ float tile[32][33];
  int z = blockIdx.z;
  const float* in = (z == 0) ? w0 : (z == 1) ? w1 : (z == 2) ? w2 : w3;
  bf16* out       = (z == 0) ? o0 : (z == 1) ? o1 : (z == 2) ? o2 : o3;
  int bx = blockIdx.x * 32, by = blockIdx.y * 32;
  int tx = threadIdx.x & 31, ty = threadIdx.x >> 5;
#pragma unroll
  for (int i = 0; i < 4; ++i)
    tile[ty + i * 8][tx] = in[(size_t)(by + ty + i * 8) * 1024 + bx + tx];
  __syncthreads();
#pragma unroll
  for (int i = 0; i < 4; ++i)
    out[(size_t)(bx + ty + i * 8) * 1024 + by + tx] = __float2bfloat16(tile[tx][ty + i * 8]);
}

// ---------------- T5 bias table: bt[h][3 + d] = rpe[bucket(d)][h] * log2(e) ----------
// stride 4104, 3 front-pad (zeros) so f32x4 loads at d-3 are always in-bounds.
__global__ __launch_bounds__(256)
void build_bias(const float* __restrict__ rpe, float* __restrict__ bt)
{
  int idx = blockIdx.x * 256 + threadIdx.x;
  if (idx >= 16 * 4104) return;
  int h = idx / 4104, j = idx - h * 4104;
  int d = j - 3;
  float v = 0.f;
  if (d >= 0 && d < 4096) {
    int b;
    if (d < 16) {
      b = d;
    } else {
      const int T[15] = {23, 32, 46, 64, 91, 128, 182, 256, 363, 512,
                         725, 1024, 1449, 2048, 2897};
      int m = 0;
#pragma unroll
      for (int i = 0; i < 15; ++i) m += (d >= T[i]);
      b = 16 + m;
    }
    v = rpe[b * 16 + h] * 1.4426950408889634f;
  }
  bt[idx] = v;
}

// ---------------- GEMM: C[4096,1024] = A @ W + bias (Wt = W^T, both bf16) ----------
// 128x128 tile, BK=64, 4 waves (2x2). global_load_lds width-16 staging:
// linear LDS dest + inverse-swizzled global source; swizzled ds_read.
template <typename OT>
__device__ __forceinline__ void gemm_body(const bf16* __restrict__ A,
                                          const bf16* __restrict__ Wt,
                                          const float* __restrict__ bias,
                                          OT* __restrict__ C, bool vt,
                                          bf16* As, bf16* Bs)
{
  const int tid = threadIdx.x;
  const int lane = tid & 63, wid = tid >> 6;
  const int l15 = lane & 15, lg = lane >> 4;
  const int wr = wid >> 1, wc = wid & 1;
  const int m0 = blockIdx.x * 128, n0 = blockIdx.y * 128;

  f32x4 acc[4][4];
#pragma unroll
  for (int i = 0; i < 4; ++i)
#pragma unroll
    for (int j = 0; j < 4; ++j) acc[i][j] = (f32x4){0.f, 0.f, 0.f, 0.f};

#pragma unroll 1
  for (int kt = 0; kt < 16; ++kt) {
    const int k0 = kt * 64;
    __syncthreads();
#pragma unroll
    for (int it = 0; it < 4; ++it) {
      const int o = tid * 16 + it * 4096;      // linear LDS byte offset this lane fills
      const int row = o >> 7;                  // 128B per row
      const int sl = ((o >> 4) & 7) ^ (row & 7);
      g2l16(A  + (size_t)(m0 + row) * 1024 + k0 + sl * 8, (char*)As + wid * 1024 + it * 4096);
      g2l16(Wt + (size_t)(n0 + row) * 1024 + k0 + sl * 8, (char*)Bs + wid * 1024 + it * 4096);
    }
    __syncthreads();

    bf16x8 af[2][4], bfr[2][4];
#pragma unroll
    for (int ks = 0; ks < 2; ++ks) {
      const int s8 = ks * 4 + lg;
#pragma unroll
      for (int f = 0; f < 4; ++f) {
        const int ra_ = wr * 64 + f * 16 + l15;
        af[ks][f]  = *(const bf16x8*)((const char*)As + ra_ * 128 + ((s8 ^ (ra_ & 7)) << 4));
        const int rb_ = wc * 64 + f * 16 + l15;
        bfr[ks][f] = *(const bf16x8*)((const char*)Bs + rb_ * 128 + ((s8 ^ (rb_ & 7)) << 4));
      }
    }
#pragma unroll
    for (int ks = 0; ks < 2; ++ks)
#pragma unroll
      for (int mf = 0; mf < 4; ++mf)
#pragma unroll
        for (int nf = 0; nf < 4; ++nf)
          acc[mf][nf] = __builtin_amdgcn_mfma_f32_16x16x32_bf16(
              af[ks][mf], bfr[ks][nf], acc[mf][nf], 0, 0, 0);
  }

#pragma unroll
  for (int nf = 0; nf < 4; ++nf) {
    const int col = n0 + wc * 64 + nf * 16 + l15;
    const float bv = bias[col];
#pragma unroll
    for (int mf = 0; mf < 4; ++mf) {
      const int rowb = m0 + wr * 64 + mf * 16 + lg * 4;
#pragma unroll
      for (int r = 0; r < 4; ++r) {
        const float val = acc[mf][nf][r] + bv;
        if constexpr (sizeof(OT) == 2) {
          if (vt)   // V stored transposed per head: C[h][d][row]
            ((bf16*)C)[((size_t)(col >> 6) << 18) + ((size_t)(col & 63) << 12) + rowb + r] =
                __float2bfloat16(val);
          else
            ((bf16*)C)[(size_t)(rowb + r) * 1024 + col] = __float2bfloat16(val);
        } else {
          ((float*)C)[(size_t)(rowb + r) * 1024 + col] = val;
        }
      }
    }
  }
}

__global__ __launch_bounds__(256)
void gemm_qkv(const bf16* __restrict__ xq, const bf16* __restrict__ xk,
              const bf16* __restrict__ xv,
              const bf16* __restrict__ wqt, const bf16* __restrict__ wkt,
              const bf16* __restrict__ wvt,
              const float* __restrict__ bq, const float* __restrict__ bk,
              const float* __restrict__ bv,
              bf16* __restrict__ Q, bf16* __restrict__ K, bf16* __restrict__ VtG)
{
  __shared__ bf16 As[128 * 64], Bs[128 * 64];
  const int z = blockIdx.z;
  gemm_body<bf16>(z == 0 ? xq : z == 1 ? xk : xv,
                  z == 0 ? wqt : z == 1 ? wkt : wvt,
                  z == 0 ? bq : z == 1 ? bk : bv,
                  z == 0 ? Q : z == 1 ? K : VtG, z == 2, As, Bs);
}

__global__ __launch_bounds__(256)
void gemm_out_k(const bf16* __restrict__ A, const bf16* __restrict__ Wt,
                const float* __restrict__ bias, float* __restrict__ C)
{
  __shared__ bf16 As[128 * 64], Bs[128 * 64];
  gemm_body<float>(A, Wt, bias, C, false, As, Bs);
}

// ---------------- causal flash attention + T5 bias (swapped QK^T) ----------------
// grid 1024; bid -> (h = bid&15, qt = 63 - bid>>4). 4 waves x 16 q-rows, KV tile 64.
// log2-domain softmax, defer-max (THR=11), vectorized bias loads, setprio on MFMA.
__global__ __launch_bounds__(256)
void attn_kernel(const bf16* __restrict__ Qb, const bf16* __restrict__ Kb,
                 const bf16* __restrict__ VtG, const float* __restrict__ bias_tab,
                 bf16* __restrict__ Ob)
{
  __shared__ bf16 Ks[64 * 64];
  __shared__ bf16 Vs[64 * 64];
  __shared__ bf16 Pl[4][16 * 76];

  const int tid = threadIdx.x;
  const int lane = tid & 63, wid = tid >> 6;
  const int l15 = lane & 15, lg = lane >> 4;
  const int bid = blockIdx.x;
  const int h  = bid & 15;
  const int qt = 63 - (bid >> 4);
  const int nt = qt + 1;
  const int qw = qt * 64 + wid * 16;
  const int q_abs = qw + l15;
  const float C1 = 0.125f * 1.4426950408889634f;   // scale * log2(e)

  const bf16* Kh = Kb + h * 64;
  const bf16* Vh = VtG + ((size_t)h << 18);
  const float* bh = bias_tab + h * 4104 + 3;
  bf16* pw = &Pl[wid][0];

  const int kr0 = tid >> 3, ks0_ = tid & 7;
  const int kr1 = (tid + 256) >> 3, ks1_ = tid & 7;

  bf16x8 qf[2];
  {
    const bf16* qp = Qb + (size_t)q_abs * 1024 + h * 64 + lg * 8;
    qf[0] = *(const bf16x8*)qp;
    qf[1] = *(const bf16x8*)(qp + 32);
  }

  f32x4 o_acc[4];
#pragma unroll
  for (int nf = 0; nf < 4; ++nf) o_acc[nf] = (f32x4){0.f, 0.f, 0.f, 0.f};
  float m_run = -1e30f, l_run = 0.f;

  // prologue: load tile 0 into regs
  bf16x8 rk0 = *(const bf16x8*)(Kh + (size_t)kr0 * 1024 + ks0_ * 8);
  bf16x8 rk1 = *(const bf16x8*)(Kh + (size_t)kr1 * 1024 + ks1_ * 8);
  bf16x8 rv0 = *(const bf16x8*)(Vh + (size_t)kr0 * 4096 + ks0_ * 8);
  bf16x8 rv1 = *(const bf16x8*)(Vh + (size_t)kr1 * 4096 + ks1_ * 8);

#pragma unroll 1
  for (int t = 0; t < nt; ++t) {
    const int k0 = t * 64;
    __syncthreads();
    {
      const int o0 = kr0 * 128 + ((ks0_ ^ (kr0 & 7)) << 4);
      const int o1 = kr1 * 128 + ((ks1_ ^ (kr1 & 7)) << 4);
      *(bf16x8*)((char*)Ks + o0) = rk0;
      *(bf16x8*)((char*)Ks + o1) = rk1;
      *(bf16x8*)((char*)Vs + o0) = rv0;
      *(bf16x8*)((char*)Vs + o1) = rv1;
    }
    __syncthreads();
    if (t + 1 < nt) {   // T14: issue next tile's loads early
      const int k1 = k0 + 64;
      rk0 = *(const bf16x8*)(Kh + (size_t)(k1 + kr0) * 1024 + ks0_ * 8);
      rk1 = *(const bf16x8*)(Kh + (size_t)(k1 + kr1) * 1024 + ks1_ * 8);
      rv0 = *(const bf16x8*)(Vh + (size_t)kr0 * 4096 + k1 + ks0_ * 8);
      rv1 = *(const bf16x8*)(Vh + (size_t)kr1 * 4096 + k1 + ks1_ * 8);
    }

    // S^T = K . Q^T : lane holds S[q = q_abs][k = k0 + kf*16 + lg*4 + r]
    f32x4 st[4];
#pragma unroll
    for (int kf = 0; kf < 4; ++kf) st[kf] = (f32x4){0.f, 0.f, 0.f, 0.f};
    __builtin_amdgcn_s_setprio(1);
#pragma unroll
    for (int kf = 0; kf < 4; ++kf) {
      const int row = kf * 16 + l15;
#pragma unroll
      for (int ks = 0; ks < 2; ++ks) {
        const int s8 = ks * 4 + lg;
        bf16x8 kfr = *(const bf16x8*)((const char*)Ks + row * 128 + ((s8 ^ (row & 7)) << 4));
        st[kf] = __builtin_amdgcn_mfma_f32_16x16x32_bf16(kfr, qf[ks], st[kf], 0, 0, 0);
      }
    }
    __builtin_amdgcn_s_setprio(0);

    // bias (vectorized, log2-domain) + mask + per-row max
    float mt = -1e30f;
#pragma unroll
    for (int kf = 0; kf < 4; ++kf) {
      const int dtop = q_abs - (k0 + kf * 16 + lg * 4);
      f32x4a b4 = (f32x4a){0.f, 0.f, 0.f, 0.f};
      if (dtop >= 0) b4 = *(const f32x4a*)(bh + dtop - 3);
#pragma unroll
      for (int r = 0; r < 4; ++r) {
        const float bb = (dtop - r >= 0) ? b4[3 - r] : -1e30f;
        const float sv = st[kf][r] * C1 + bb;
        st[kf][r] = sv;
        mt = fmaxf(mt, sv);
      }
    }
    mt = fmaxf(mt, __shfl_xor(mt, 16, 64));
    mt = fmaxf(mt, __shfl_xor(mt, 32, 64));

    // T13 defer-max: only rescale when tile max beats running max by >11 (log2)
    if (__any(mt > m_run + 11.0f)) {
      const float newm = fmaxf(m_run, mt);
      const float sc = (m_run > -1e29f) ? exp2f(m_run - newm) : 0.f;
      m_run = newm;
      float scr[4];
#pragma unroll
      for (int r = 0; r < 4; ++r) scr[r] = __shfl(sc, lg * 4 + r, 64);
#pragma unroll
      for (int nf = 0; nf < 4; ++nf)
#pragma unroll
        for (int r = 0; r < 4; ++r) o_acc[nf][r] *= scr[r];
      l_run *= sc;
    }

    float rs = 0.f;
    bf16x4 pk[4];
#pragma unroll
    for (int kf = 0; kf < 4; ++kf)
#pragma unroll
      for (int r = 0; r < 4; ++r) {
        const float p = (st[kf][r] > -1e29f) ? exp2f(st[kf][r] - m_run) : 0.f;
        ((bf16*)&pk[kf])[r] = __float2bfloat16(p);
        rs += p;
      }
    rs += __shfl_xor(rs, 16, 64);
    rs += __shfl_xor(rs, 32, 64);
    l_run += rs;

    // P strip: lane writes its 4 consecutive k per kf (b64)
#pragma unroll
    for (int kf = 0; kf < 4; ++kf)
      *(bf16x4*)&pw[l15 * 76 + kf * 16 + lg * 4] = pk[kf];

    // PV: A = P (q rows), B = V^T-staged (d cols, k contiguous)
    bf16x8 pf[2];
#pragma unroll
    for (int ks2 = 0; ks2 < 2; ++ks2)
      pf[ks2] = *(const bf16x8*)&pw[l15 * 76 + ks2 * 32 + lg * 8];
    __builtin_amdgcn_s_setprio(1);
#pragma unroll
    for (int ks2 = 0; ks2 < 2; ++ks2)
#pragma unroll
      for (int nf = 0; nf < 4; ++nf) {
        const int row = nf * 16 + l15;
        const int s8 = ks2 * 4 + lg;
        bf16x8 vfr = *(const bf16x8*)((const char*)Vs + row * 128 + ((s8 ^ (row & 7)) << 4));
        o_acc[nf] = __builtin_amdgcn_mfma_f32_16x16x32_bf16(pf[ks2], vfr, o_acc[nf], 0, 0, 0);
      }
    __builtin_amdgcn_s_setprio(0);
  }

  // epilogue: O / l, store [S, H*64]
  const float linv = 1.f / l_run;
  float lr[4];
#pragma unroll
  for (int r = 0; r < 4; ++r) lr[r] = __shfl(linv, lg * 4 + r, 64);
#pragma unroll
  for (int nf = 0; nf < 4; ++nf)
#pragma unroll
    for (int r = 0; r < 4; ++r) {
      const int row = qw + lg * 4 + r;
      Ob[(size_t)row * 1024 + h * 64 + nf * 16 + l15] =
          __float2bfloat16(o_acc[nf][r] * lr[r]);
    }
}

// ---------------- launch ----------------
extern "C" void kernel_launch(void* const* d_in, const int* in_sizes, int n_in,
                              void* d_out, int out_size, void* d_ws, size_t ws_size,
                              hipStream_t stream) {
  (void)in_sizes; (void)n_in; (void)out_size; (void)ws_size;
  const float* q   = (const float*)d_in[0];
  const float* k   = (const float*)d_in[1];
  const float* v   = (const float*)d_in[2];
  // d_in[3] = causal mask, deterministic -> ignored
  const float* Wq  = (const float*)d_in[4];
  const float* bq  = (const float*)d_in[5];
  const float* Wk  = (const float*)d_in[6];
  const float* bk  = (const float*)d_in[7];
  const float* Wv  = (const float*)d_in[8];
  const float* bv  = (const float*)d_in[9];
  const float* Wo  = (const float*)d_in[10];
  const float* bo  = (const float*)d_in[11];
  const float* rpe = (const float*)d_in[12];
  float* out = (float*)d_out;

  char* ws = (char*)d_ws;
  bf16* WqT   = (bf16*)(ws + (size_t)0);
  bf16* WkT   = (bf16*)(ws + ((size_t)2  << 20));
  bf16* WvT   = (bf16*)(ws + ((size_t)4  << 20));
  bf16* WoT   = (bf16*)(ws + ((size_t)6  << 20));
  bf16* xq_bf = (bf16*)(ws + ((size_t)8  << 20));
  bf16* xk_bf = (bf16*)(ws + ((size_t)16 << 20));
  bf16* xv_bf = (bf16*)(ws + ((size_t)24 << 20));
  bf16* Qb    = (bf16*)(ws + ((size_t)32 << 20));
  bf16* Kb    = (bf16*)(ws + ((size_t)40 << 20));
  bf16* VtG   = (bf16*)(ws + ((size_t)48 << 20));   // [16][64][4096]
  float* bias_tab = (float*)(ws + ((size_t)56 << 20));
  bf16* Ob    = xq_bf;   // xq_bf dead after gemm_qkv; reuse for attn output

  transpose_w<<<dim3(32, 32, 4), 256, 0, stream>>>(Wq, Wk, Wv, Wo, WqT, WkT, WvT, WoT);
  build_bias<<<dim3(257), 256, 0, stream>>>(rpe, bias_tab);
  cvt_bf16<<<dim3(2048, 1, 3), 256, 0, stream>>>(q, k, v, xq_bf, xk_bf, xv_bf);
  gemm_qkv<<<dim3(32, 8, 3), 256, 0, stream>>>(xq_bf, xk_bf, xv_bf, WqT, WkT, WvT,
                                               bq, bk, bv, Qb, Kb, VtG);
  attn_kernel<<<dim3(1024), 256, 0, stream>>>(Qb, Kb, VtG, bias_tab, Ob);
  gemm_out_k<<<dim3(32, 8), 256, 0, stream>>>(Ob, WoT, bo, out);
}